// Round 1
// baseline (3284.132 us; speedup 1.0000x reference)
//
#include <hip/hip_runtime.h>

#define Nn 100000
#define INC 256
#define OC 40

// Mp[128][256]: rows j=40*i+o (j<120) = sum_t fc_out_w[o][i*64+t] * fc1_w[t][:]
// rows 120..127 are zero padding (read by GEMM staging, results discarded).
__global__ void make_M(const float* __restrict__ fc1_w,    // [64,256]
                       const float* __restrict__ fc_out_w, // [40,192]
                       float* __restrict__ Mp) {
    int j = blockIdx.x;   // 0..127
    int k = threadIdx.x;  // 0..255
    float acc = 0.f;
    if (j < 120) {
        int i = j / 40, o = j - i * 40;
        const float* wrow = fc_out_w + o * 192 + i * 64;
#pragma unroll 8
        for (int t = 0; t < 64; ++t)
            acc = fmaf(wrow[t], fc1_w[t * 256 + k], acc);
    }
    Mp[j * 256 + k] = acc;
}

// g = x @ Mp^T.  Block tile: 64 rows x 128 cols (120 used), K-tile 64.
// cols 0..39 -> out (+bias), 40..79 -> g1, 80..119 -> g2.
__global__ __launch_bounds__(256, 2) void gemm_g(
    const float* __restrict__ x,    // [N,256]
    const float* __restrict__ Mp,   // [128,256]
    const float* __restrict__ bias, // [40]
    float* __restrict__ out,        // [N,40]
    float* __restrict__ g1,         // [N,40]
    float* __restrict__ g2) {
    __shared__ float xs[64 * 65];   // stride 65: 2-way bank alias (free)
    __shared__ float ms[128 * 65];
    const int tid = threadIdx.x;
    const int ty = tid & 15;   // row group: rows ty*4..ty*4+3
    const int tx = tid >> 4;   // col group: cols tx*8..tx*8+7
    const int row0 = blockIdx.x * 64;

    float acc[4][8];
#pragma unroll
    for (int i = 0; i < 4; ++i)
#pragma unroll
        for (int j = 0; j < 8; ++j) acc[i][j] = 0.f;

    for (int kb = 0; kb < INC; kb += 64) {
        // stage x tile: 64x64 floats = 1024 float4 slots, 4 per thread
#pragma unroll
        for (int i = 0; i < 4; ++i) {
            int lin = tid + i * 256;
            int r = lin >> 4;            // 16 float4 per row
            int k4 = (lin & 15) << 2;
            float4 v = make_float4(0.f, 0.f, 0.f, 0.f);
            int gr = row0 + r;
            if (gr < Nn) v = *(const float4*)(x + gr * INC + kb + k4);
            float* p = xs + r * 65 + k4;
            p[0] = v.x; p[1] = v.y; p[2] = v.z; p[3] = v.w;
        }
        // stage M tile: 128x64 floats = 2048 float4 slots, 8 per thread
#pragma unroll
        for (int i = 0; i < 8; ++i) {
            int lin = tid + i * 256;
            int r = lin >> 4;
            int k4 = (lin & 15) << 2;
            float4 v = *(const float4*)(Mp + r * 256 + kb + k4);
            float* p = ms + r * 65 + k4;
            p[0] = v.x; p[1] = v.y; p[2] = v.z; p[3] = v.w;
        }
        __syncthreads();
#pragma unroll 8
        for (int k = 0; k < 64; ++k) {
            float a[4], b[8];
#pragma unroll
            for (int i = 0; i < 4; ++i) a[i] = xs[(ty * 4 + i) * 65 + k];
#pragma unroll
            for (int j = 0; j < 8; ++j) b[j] = ms[(tx * 8 + j) * 65 + k];
#pragma unroll
            for (int i = 0; i < 4; ++i)
#pragma unroll
                for (int j = 0; j < 8; ++j)
                    acc[i][j] = fmaf(a[i], b[j], acc[i][j]);
        }
        __syncthreads();
    }

    // epilogue: route 8-col chunk to out/g1/g2 (8 | 40, so no straddling)
    const int c0 = tx * 8;
    if (c0 < 120) {
        int ib = c0 / 40;
        int o0 = c0 - ib * 40;
        float* dbuf = (ib == 0) ? out : (ib == 1 ? g1 : g2);
        float badd[8];
#pragma unroll
        for (int j = 0; j < 8; ++j) badd[j] = (ib == 0) ? bias[o0 + j] : 0.f;
#pragma unroll
        for (int i = 0; i < 4; ++i) {
            int n = row0 + ty * 4 + i;
            if (n < Nn) {
                float4 v0 = make_float4(acc[i][0] + badd[0], acc[i][1] + badd[1],
                                        acc[i][2] + badd[2], acc[i][3] + badd[3]);
                float4 v1 = make_float4(acc[i][4] + badd[4], acc[i][5] + badd[5],
                                        acc[i][6] + badd[6], acc[i][7] + badd[7]);
                *(float4*)(dbuf + n * 40 + o0) = v0;
                *(float4*)(dbuf + n * 40 + o0 + 4) = v1;
            }
        }
    }
}

// out[src[e]*40 + c] += val[e] * g[dst[e]*40 + c], 40 ch as 10 float4 groups.
// Block 320 threads = 32 edges x 10 float4-lanes.
__global__ __launch_bounds__(320) void edge_scatter(
    const int* __restrict__ src, const int* __restrict__ dst,
    const float* __restrict__ val, const float* __restrict__ g,
    float* __restrict__ out, int nE) {
    int le = threadIdx.x / 10;       // 0..31 (magic-mul)
    int q  = threadIdx.x - le * 10;  // 0..9
    int e = blockIdx.x * 32 + le;
    if (e >= nE) return;
    int s = src[e], d = dst[e];
    float v = val[e];
    float4 gg = *(const float4*)(g + d * 40 + q * 4);
    float* po = out + s * 40 + q * 4;
    atomicAdd(po + 0, v * gg.x);
    atomicAdd(po + 1, v * gg.y);
    atomicAdd(po + 2, v * gg.z);
    atomicAdd(po + 3, v * gg.w);
}

extern "C" void kernel_launch(void* const* d_in, const int* in_sizes, int n_in,
                              void* d_out, int out_size, void* d_ws, size_t ws_size,
                              hipStream_t stream) {
    const float* x        = (const float*)d_in[0];
    // d_in[1] = edge_index: unused by the reference
    const int*   adj_src  = (const int*)d_in[2];
    const int*   adj_dst  = (const int*)d_in[3];
    const float* adj_val  = (const float*)d_in[4];
    const int*   adj2_src = (const int*)d_in[5];
    const int*   adj2_dst = (const int*)d_in[6];
    const float* adj2_val = (const float*)d_in[7];
    const float* fc1_w    = (const float*)d_in[8];
    const float* fc_out_w = (const float*)d_in[9];
    const float* fc_out_b = (const float*)d_in[10];
    float* out = (float*)d_out;

    char* ws = (char*)d_ws;
    float* Mp = (float*)ws;                            // 128*256*4 = 131072 B
    float* g1 = (float*)(ws + 131072);                 // N*40*4 = 16 MB
    float* g2 = (float*)(ws + 131072 + 16000000);      // N*40*4 = 16 MB

    const int E1 = in_sizes[2];
    const int E2 = in_sizes[5];

    make_M<<<128, 256, 0, stream>>>(fc1_w, fc_out_w, Mp);
    gemm_g<<<(Nn + 63) / 64, 256, 0, stream>>>(x, Mp, fc_out_b, out, g1, g2);
    edge_scatter<<<(E1 + 31) / 32, 320, 0, stream>>>(adj_src, adj_dst, adj_val, g1, out, E1);
    edge_scatter<<<(E2 + 31) / 32, 320, 0, stream>>>(adj2_src, adj2_dst, adj2_val, g2, out, E2);
}

// Round 2
// 3282.466 us; speedup vs baseline: 1.0005x; 1.0005x over previous
//
#include <hip/hip_runtime.h>

#define Nn 100000
#define INC 256
#define OC 40

// Mp[128][256]: rows j=40*i+o (j<120) = sum_t fc_out_w[o][i*64+t] * fc1_w[t][:]
// rows 120..127 are zero padding (read by GEMM staging, results discarded).
__global__ void make_M(const float* __restrict__ fc1_w,    // [64,256]
                       const float* __restrict__ fc_out_w, // [40,192]
                       float* __restrict__ Mp) {
    int j = blockIdx.x;   // 0..127
    int k = threadIdx.x;  // 0..255
    float acc = 0.f;
    if (j < 120) {
        int i = j / 40, o = j - i * 40;
        const float* wrow = fc_out_w + o * 192 + i * 64;
#pragma unroll 8
        for (int t = 0; t < 64; ++t)
            acc = fmaf(wrow[t], fc1_w[t * 256 + k], acc);
    }
    Mp[j * 256 + k] = acc;
}

// g = x @ Mp^T.  Block tile: 64 rows x 128 cols (120 used), K-tile 64.
// cols 0..39 -> out (+bias), 40..79 -> g1, 80..119 -> g2.
__global__ __launch_bounds__(256, 2) void gemm_g(
    const float* __restrict__ x,    // [N,256]
    const float* __restrict__ Mp,   // [128,256]
    const float* __restrict__ bias, // [40]
    float* __restrict__ out,        // [N,40]
    float* __restrict__ g1,         // [N,40]
    float* __restrict__ g2) {
    __shared__ float xs[64 * 65];   // stride 65: 2-way bank alias (free)
    __shared__ float ms[128 * 65];
    const int tid = threadIdx.x;
    const int ty = tid & 15;   // row group: rows ty*4..ty*4+3
    const int tx = tid >> 4;   // col group: cols tx*8..tx*8+7
    const int row0 = blockIdx.x * 64;

    float acc[4][8];
#pragma unroll
    for (int i = 0; i < 4; ++i)
#pragma unroll
        for (int j = 0; j < 8; ++j) acc[i][j] = 0.f;

    for (int kb = 0; kb < INC; kb += 64) {
        // stage x tile: 64x64 floats = 1024 float4 slots, 4 per thread
#pragma unroll
        for (int i = 0; i < 4; ++i) {
            int lin = tid + i * 256;
            int r = lin >> 4;            // 16 float4 per row
            int k4 = (lin & 15) << 2;
            float4 v = make_float4(0.f, 0.f, 0.f, 0.f);
            int gr = row0 + r;
            if (gr < Nn) v = *(const float4*)(x + gr * INC + kb + k4);
            float* p = xs + r * 65 + k4;
            p[0] = v.x; p[1] = v.y; p[2] = v.z; p[3] = v.w;
        }
        // stage M tile: 128x64 floats = 2048 float4 slots, 8 per thread
#pragma unroll
        for (int i = 0; i < 8; ++i) {
            int lin = tid + i * 256;
            int r = lin >> 4;
            int k4 = (lin & 15) << 2;
            float4 v = *(const float4*)(Mp + r * 256 + kb + k4);
            float* p = ms + r * 65 + k4;
            p[0] = v.x; p[1] = v.y; p[2] = v.z; p[3] = v.w;
        }
        __syncthreads();
#pragma unroll 8
        for (int k = 0; k < 64; ++k) {
            float a[4], b[8];
#pragma unroll
            for (int i = 0; i < 4; ++i) a[i] = xs[(ty * 4 + i) * 65 + k];
#pragma unroll
            for (int j = 0; j < 8; ++j) b[j] = ms[(tx * 8 + j) * 65 + k];
#pragma unroll
            for (int i = 0; i < 4; ++i)
#pragma unroll
                for (int j = 0; j < 8; ++j)
                    acc[i][j] = fmaf(a[i], b[j], acc[i][j]);
        }
        __syncthreads();
    }

    // epilogue: route 8-col chunk to out/g1/g2 (8 | 40, so no straddling)
    const int c0 = tx * 8;
    if (c0 < 120) {
        int ib = c0 / 40;
        int o0 = c0 - ib * 40;
        float* dbuf = (ib == 0) ? out : (ib == 1 ? g1 : g2);
        float badd[8];
#pragma unroll
        for (int j = 0; j < 8; ++j) badd[j] = (ib == 0) ? bias[o0 + j] : 0.f;
#pragma unroll
        for (int i = 0; i < 4; ++i) {
            int n = row0 + ty * 4 + i;
            if (n < Nn) {
                float4 v0 = make_float4(acc[i][0] + badd[0], acc[i][1] + badd[1],
                                        acc[i][2] + badd[2], acc[i][3] + badd[3]);
                float4 v1 = make_float4(acc[i][4] + badd[4], acc[i][5] + badd[5],
                                        acc[i][6] + badd[6], acc[i][7] + badd[7]);
                *(float4*)(dbuf + n * 40 + o0) = v0;
                *(float4*)(dbuf + n * 40 + o0 + 4) = v1;
            }
        }
    }
}

// out[src[e]*40 + c] += val[e] * g[dst[e]*40 + c], 40 ch as 10 float4 groups.
// Block 320 threads = 32 edges x 10 float4-lanes.
// unsafeAtomicAdd -> hardware global_atomic_add_f32 (completes in L2),
// vs default atomicAdd's CAS loop (R1: 2 GB HBM write traffic, 2 ms).
__global__ __launch_bounds__(320) void edge_scatter(
    const int* __restrict__ src, const int* __restrict__ dst,
    const float* __restrict__ val, const float* __restrict__ g,
    float* __restrict__ out, int nE) {
    int le = threadIdx.x / 10;       // 0..31 (magic-mul)
    int q  = threadIdx.x - le * 10;  // 0..9
    int e = blockIdx.x * 32 + le;
    if (e >= nE) return;
    int s = src[e], d = dst[e];
    float v = val[e];
    float4 gg = *(const float4*)(g + d * 40 + q * 4);
    float* po = out + s * 40 + q * 4;
    unsafeAtomicAdd(po + 0, v * gg.x);
    unsafeAtomicAdd(po + 1, v * gg.y);
    unsafeAtomicAdd(po + 2, v * gg.z);
    unsafeAtomicAdd(po + 3, v * gg.w);
}

extern "C" void kernel_launch(void* const* d_in, const int* in_sizes, int n_in,
                              void* d_out, int out_size, void* d_ws, size_t ws_size,
                              hipStream_t stream) {
    const float* x        = (const float*)d_in[0];
    // d_in[1] = edge_index: unused by the reference
    const int*   adj_src  = (const int*)d_in[2];
    const int*   adj_dst  = (const int*)d_in[3];
    const float* adj_val  = (const float*)d_in[4];
    const int*   adj2_src = (const int*)d_in[5];
    const int*   adj2_dst = (const int*)d_in[6];
    const float* adj2_val = (const float*)d_in[7];
    const float* fc1_w    = (const float*)d_in[8];
    const float* fc_out_w = (const float*)d_in[9];
    const float* fc_out_b = (const float*)d_in[10];
    float* out = (float*)d_out;

    char* ws = (char*)d_ws;
    float* Mp = (float*)ws;                            // 128*256*4 = 131072 B
    float* g1 = (float*)(ws + 131072);                 // N*40*4 = 16 MB
    float* g2 = (float*)(ws + 131072 + 16000000);      // N*40*4 = 16 MB

    const int E1 = in_sizes[2];
    const int E2 = in_sizes[5];

    make_M<<<128, 256, 0, stream>>>(fc1_w, fc_out_w, Mp);
    gemm_g<<<(Nn + 63) / 64, 256, 0, stream>>>(x, Mp, fc_out_b, out, g1, g2);
    edge_scatter<<<(E1 + 31) / 32, 320, 0, stream>>>(adj_src, adj_dst, adj_val, g1, out, E1);
    edge_scatter<<<(E2 + 31) / 32, 320, 0, stream>>>(adj2_src, adj2_dst, adj2_val, g2, out, E2);
}

// Round 3
// 1175.827 us; speedup vs baseline: 2.7930x; 2.7916x over previous
//
#include <hip/hip_runtime.h>

#define Nn 100000
#define INC 256
#define OC 40
#define GFLOATS 4000000            // N*40 floats per g buffer
#define NEDGE_TOT 4800000

// ---- workspace layout (bytes) ----
#define MP_OFF   0                 // 128*256*4 = 131072
#define G_OFF    131072            // g1 then g2, 16,000,000 B each
#define CNT_OFF  32131072          // counts: 100000 ints
#define RS_OFF   32535072          // row_start: 100001 ints
#define CUR_OFF  32939072          // cursor: 100000 ints
#define PAY_OFF  33343072          // payload: 4.8M * uint2 = 38,400,000
#define WS_NEED  (PAY_OFF + (size_t)NEDGE_TOT * 8)

// Mp[128][256]: rows j=40*i+o (j<120) = sum_t fc_out_w[o][i*64+t] * fc1_w[t][:]
__global__ void make_M(const float* __restrict__ fc1_w,
                       const float* __restrict__ fc_out_w,
                       float* __restrict__ Mp) {
    int j = blockIdx.x;   // 0..127
    int k = threadIdx.x;  // 0..255
    float acc = 0.f;
    if (j < 120) {
        int i = j / 40, o = j - i * 40;
        const float* wrow = fc_out_w + o * 192 + i * 64;
#pragma unroll 8
        for (int t = 0; t < 64; ++t)
            acc = fmaf(wrow[t], fc1_w[t * 256 + k], acc);
    }
    Mp[j * 256 + k] = acc;
}

// g = x @ Mp^T.  Block tile: 64 rows x 128 cols (120 used), K-tile 64.
__global__ __launch_bounds__(256, 2) void gemm_g(
    const float* __restrict__ x, const float* __restrict__ Mp,
    const float* __restrict__ bias, float* __restrict__ out,
    float* __restrict__ g1, float* __restrict__ g2) {
    __shared__ float xs[64 * 65];
    __shared__ float ms[128 * 65];
    const int tid = threadIdx.x;
    const int ty = tid & 15;
    const int tx = tid >> 4;
    const int row0 = blockIdx.x * 64;

    float acc[4][8];
#pragma unroll
    for (int i = 0; i < 4; ++i)
#pragma unroll
        for (int j = 0; j < 8; ++j) acc[i][j] = 0.f;

    for (int kb = 0; kb < INC; kb += 64) {
#pragma unroll
        for (int i = 0; i < 4; ++i) {
            int lin = tid + i * 256;
            int r = lin >> 4;
            int k4 = (lin & 15) << 2;
            float4 v = make_float4(0.f, 0.f, 0.f, 0.f);
            int gr = row0 + r;
            if (gr < Nn) v = *(const float4*)(x + gr * INC + kb + k4);
            float* p = xs + r * 65 + k4;
            p[0] = v.x; p[1] = v.y; p[2] = v.z; p[3] = v.w;
        }
#pragma unroll
        for (int i = 0; i < 8; ++i) {
            int lin = tid + i * 256;
            int r = lin >> 4;
            int k4 = (lin & 15) << 2;
            float4 v = *(const float4*)(Mp + r * 256 + kb + k4);
            float* p = ms + r * 65 + k4;
            p[0] = v.x; p[1] = v.y; p[2] = v.z; p[3] = v.w;
        }
        __syncthreads();
#pragma unroll 8
        for (int k = 0; k < 64; ++k) {
            float a[4], b[8];
#pragma unroll
            for (int i = 0; i < 4; ++i) a[i] = xs[(ty * 4 + i) * 65 + k];
#pragma unroll
            for (int j = 0; j < 8; ++j) b[j] = ms[(tx * 8 + j) * 65 + k];
#pragma unroll
            for (int i = 0; i < 4; ++i)
#pragma unroll
                for (int j = 0; j < 8; ++j)
                    acc[i][j] = fmaf(a[i], b[j], acc[i][j]);
        }
        __syncthreads();
    }

    const int c0 = tx * 8;
    if (c0 < 120) {
        int ib = c0 / 40;
        int o0 = c0 - ib * 40;
        float* dbuf = (ib == 0) ? out : (ib == 1 ? g1 : g2);
        float badd[8];
#pragma unroll
        for (int j = 0; j < 8; ++j) badd[j] = (ib == 0) ? bias[o0 + j] : 0.f;
#pragma unroll
        for (int i = 0; i < 4; ++i) {
            int n = row0 + ty * 4 + i;
            if (n < Nn) {
                float4 v0 = make_float4(acc[i][0] + badd[0], acc[i][1] + badd[1],
                                        acc[i][2] + badd[2], acc[i][3] + badd[3]);
                float4 v1 = make_float4(acc[i][4] + badd[4], acc[i][5] + badd[5],
                                        acc[i][6] + badd[6], acc[i][7] + badd[7]);
                *(float4*)(dbuf + n * 40 + o0) = v0;
                *(float4*)(dbuf + n * 40 + o0 + 4) = v1;
            }
        }
    }
}

// ---- CSR build ----
__global__ void hist_kernel(const int* __restrict__ src, int nE,
                            int* __restrict__ counts) {
    int e = blockIdx.x * 256 + threadIdx.x;
    if (e < nE) atomicAdd(&counts[src[e]], 1);
}

// single-block exclusive scan of counts[100000] -> row_start[100001]
__global__ __launch_bounds__(1024) void scan_kernel(const int* __restrict__ counts,
                                                    int* __restrict__ row_start) {
    __shared__ int sm[1024];
    const int t = threadIdx.x;
    const int CH = 98;  // 1024*98 >= 100000
    int lo = t * CH, hi = min(lo + CH, Nn);
    int s = 0;
    for (int i = lo; i < hi; ++i) s += counts[i];
    sm[t] = s;
    __syncthreads();
    for (int off = 1; off < 1024; off <<= 1) {
        int v = (t >= off) ? sm[t - off] : 0;
        __syncthreads();
        sm[t] += v;
        __syncthreads();
    }
    int run = sm[t] - s;  // exclusive base for this chunk
    for (int i = lo; i < hi; ++i) { row_start[i] = run; run += counts[i]; }
    if (t == 1023) row_start[Nn] = sm[1023];
}

__global__ void copy_cursor(const int* __restrict__ row_start,
                            int* __restrict__ cursor) {
    int i = blockIdx.x * 256 + threadIdx.x;
    if (i < Nn) cursor[i] = row_start[i];
}

// payload: x = dst | (graph<<17), y = bits(val)
__global__ void fill_kernel(const int* __restrict__ src, const int* __restrict__ dst,
                            const float* __restrict__ val, int nE, int graph,
                            int* __restrict__ cursor, uint2* __restrict__ payload) {
    int e = blockIdx.x * 256 + threadIdx.x;
    if (e >= nE) return;
    int pos = atomicAdd(&cursor[src[e]], 1);
    payload[pos] = make_uint2((unsigned)dst[e] | ((unsigned)graph << 17),
                              __float_as_uint(val[e]));
}

// gather: 10 threads per row, each owns one float4 of the 40 channels.
// out[row] += sum_e val * g[graph][dst]; no atomics (row exclusively owned).
__global__ __launch_bounds__(320) void gather_kernel(
    const int* __restrict__ row_start, const uint2* __restrict__ payload,
    const float* __restrict__ g,   // g1 followed by g2 (GFLOATS each)
    float* __restrict__ out) {
    int le = threadIdx.x / 10;
    int q = threadIdx.x - le * 10;
    int row = blockIdx.x * 32 + le;
    if (row >= Nn) return;
    int e = row_start[row], eend = row_start[row + 1];
    float4 acc = make_float4(0.f, 0.f, 0.f, 0.f);
    for (; e < eend; ++e) {
        uint2 p = payload[e];                 // same addr across the 10 lanes
        float v = __uint_as_float(p.y);
        int base = (int)(p.x & 0x1FFFFu) * 40 + (int)(p.x >> 17) * GFLOATS;
        float4 gg = *(const float4*)(g + base + q * 4);
        acc.x = fmaf(v, gg.x, acc.x);
        acc.y = fmaf(v, gg.y, acc.y);
        acc.z = fmaf(v, gg.z, acc.z);
        acc.w = fmaf(v, gg.w, acc.w);
    }
    float* po = out + row * 40 + q * 4;
    float4 o = *(float4*)po;
    o.x += acc.x; o.y += acc.y; o.z += acc.z; o.w += acc.w;
    *(float4*)po = o;
}

// fallback (ws too small): direct fp-atomic scatter
__global__ __launch_bounds__(320) void edge_scatter(
    const int* __restrict__ src, const int* __restrict__ dst,
    const float* __restrict__ val, const float* __restrict__ g,
    float* __restrict__ out, int nE) {
    int le = threadIdx.x / 10;
    int q = threadIdx.x - le * 10;
    int e = blockIdx.x * 32 + le;
    if (e >= nE) return;
    int s = src[e], d = dst[e];
    float v = val[e];
    float4 gg = *(const float4*)(g + d * 40 + q * 4);
    float* po = out + s * 40 + q * 4;
    unsafeAtomicAdd(po + 0, v * gg.x);
    unsafeAtomicAdd(po + 1, v * gg.y);
    unsafeAtomicAdd(po + 2, v * gg.z);
    unsafeAtomicAdd(po + 3, v * gg.w);
}

extern "C" void kernel_launch(void* const* d_in, const int* in_sizes, int n_in,
                              void* d_out, int out_size, void* d_ws, size_t ws_size,
                              hipStream_t stream) {
    const float* x        = (const float*)d_in[0];
    const int*   adj_src  = (const int*)d_in[2];
    const int*   adj_dst  = (const int*)d_in[3];
    const float* adj_val  = (const float*)d_in[4];
    const int*   adj2_src = (const int*)d_in[5];
    const int*   adj2_dst = (const int*)d_in[6];
    const float* adj2_val = (const float*)d_in[7];
    const float* fc1_w    = (const float*)d_in[8];
    const float* fc_out_w = (const float*)d_in[9];
    const float* fc_out_b = (const float*)d_in[10];
    float* out = (float*)d_out;

    char* ws = (char*)d_ws;
    float* Mp = (float*)(ws + MP_OFF);
    float* g1 = (float*)(ws + G_OFF);
    float* g2 = g1 + GFLOATS;

    const int E1 = in_sizes[2];
    const int E2 = in_sizes[5];

    make_M<<<128, 256, 0, stream>>>(fc1_w, fc_out_w, Mp);
    gemm_g<<<(Nn + 63) / 64, 256, 0, stream>>>(x, Mp, fc_out_b, out, g1, g2);

    if (ws_size >= WS_NEED) {
        int*   counts    = (int*)(ws + CNT_OFF);
        int*   row_start = (int*)(ws + RS_OFF);
        int*   cursor    = (int*)(ws + CUR_OFF);
        uint2* payload   = (uint2*)(ws + PAY_OFF);

        hipMemsetAsync(counts, 0, Nn * sizeof(int), stream);
        hist_kernel<<<(E1 + 255) / 256, 256, 0, stream>>>(adj_src, E1, counts);
        hist_kernel<<<(E2 + 255) / 256, 256, 0, stream>>>(adj2_src, E2, counts);
        scan_kernel<<<1, 1024, 0, stream>>>(counts, row_start);
        copy_cursor<<<(Nn + 255) / 256, 256, 0, stream>>>(row_start, cursor);
        fill_kernel<<<(E1 + 255) / 256, 256, 0, stream>>>(adj_src, adj_dst, adj_val,
                                                          E1, 0, cursor, payload);
        fill_kernel<<<(E2 + 255) / 256, 256, 0, stream>>>(adj2_src, adj2_dst, adj2_val,
                                                          E2, 1, cursor, payload);
        gather_kernel<<<(Nn + 31) / 32, 320, 0, stream>>>(row_start, payload, g1, out);
    } else {
        edge_scatter<<<(E1 + 31) / 32, 320, 0, stream>>>(adj_src, adj_dst, adj_val, g1, out, E1);
        edge_scatter<<<(E2 + 31) / 32, 320, 0, stream>>>(adj2_src, adj2_dst, adj2_val, g2, out, E2);
    }
}